// Round 3
// baseline (801.529 us; speedup 1.0000x reference)
//
#include <hip/hip_runtime.h>
#include <stdint.h>

// Problem constants
#define B_    256
#define T_    512
#define DIN   512
#define H_    512
#define NEMB_ 96
#define BT    131072   // B_*T_

typedef __attribute__((ext_vector_type(8))) short short8;    // 8 bf16 (4 VGPRs)
typedef __attribute__((ext_vector_type(4))) float f32x4;
typedef __attribute__((ext_vector_type(16))) float f32x16;

__device__ __forceinline__ unsigned bf16_rne(float f) {
    unsigned u = __float_as_uint(f);
    return (u + 0x7FFF + ((u >> 16) & 1)) >> 16;
}
__device__ __forceinline__ unsigned pack2(float a, float b) {
    return bf16_rne(a) | (bf16_rne(b) << 16);
}
__device__ __forceinline__ float tanh_fast(float x) {
    float ex = __expf(2.f * x);
    return 1.f - 2.f / (ex + 1.f);
}
__device__ __forceinline__ float sigmoid_fast(float x) {
    return 1.f / (1.f + __expf(-x));
}

// ---------------- kernel 0: Wi2h fp32 -> bf16 ----------------
__global__ void k_cvt(const float* __restrict__ W, unsigned* __restrict__ Wb) {
    int i = blockIdx.x * 256 + threadIdx.x;          // 131072 uints (2 bf16 each)
    float2 f = ((const float2*)W)[i];
    Wb[i] = pack2(f.x, f.y);
}

// ---------------- kernel 1: prevproj = h @ Wh2h^T + bh2h ----------------
// Coalesced: each wave computes 8 outputs (t), 8 lanes split k.
// grid = 256 b * 16 t-chunks; 256 threads = 4 waves * 8 t = 32 t per block.
__global__ void k_prevproj(const float* __restrict__ hin, const float* __restrict__ Whh,
                           const float* __restrict__ bh, float* __restrict__ pp) {
    __shared__ float hs[512];
    int b = blockIdx.x >> 4, tc = blockIdx.x & 15;
    int tid = threadIdx.x;
    hs[tid]       = hin[b * 512 + tid];
    hs[256 + tid] = hin[b * 512 + 256 + tid];
    __syncthreads();
    int wave = tid >> 6, lane = tid & 63;
    int o = lane >> 3, kg = lane & 7;
    int t = tc * 32 + wave * 8 + o;
    const float4* wr = (const float4*)(Whh + (size_t)t * 512);
    const float4* hv = (const float4*)hs;
    float acc = 0.f;
#pragma unroll
    for (int j = 0; j < 16; ++j) {
        float4 w = wr[j * 8 + kg];
        float4 x = hv[j * 8 + kg];
        acc += w.x * x.x + w.y * x.y + w.z * x.z + w.w * x.w;
    }
#pragma unroll
    for (int off = 1; off < 8; off <<= 1) acc += __shfl_xor(acc, off, 8);
    if (kg == 0) pp[b * 512 + t] = acc + bh[t];
}

// ---------------- kernel 2: attention scores (fused GEMM+tanh+dot) -----------
// e[b,t] = sum_h Wscore[h] * tanh( sum_d batch_H[b,t,d]*Wi2h[h,d] + pp[b,h] )
// BM=64 rows/block, 512 threads = 8 waves; wave w owns cols [w*64, w*64+64)
// (block reads Wb exactly once). 32x32x16 MFMA, 2x2 register tile per wave
// (64 rows x 64 cols = 4 f32x16 accs). No persistent eacc: tanh+Wscore dot is
// reduced immediately per tile via width-32 shuffles -> no spills.
// A tile 64x512 bf16 = 64KB LDS, XOR-swizzled 16B slots:
//   slot(row, g) = row*64 + (g ^ (row&7)),  g = k/8  (0..63)
__launch_bounds__(512, 4)
__global__ void k_scores(const float* __restrict__ A,              // batch_H [BT,512]
                         const unsigned short* __restrict__ Wb,    // bf16 Wi2h [512,512]
                         const float* __restrict__ pp,             // [B_,512]
                         const float* __restrict__ wsc,            // Wscore [512]
                         float* __restrict__ e)                    // [BT]
{
    __shared__ uint4 ldsA[4096];                                   // 65536 B
    __shared__ float es[64];
    int tid = threadIdx.x;
    int blockRow = blockIdx.x * 64;
    int b = blockRow >> 9;                                         // 8 blocks per batch row
    int lane = tid & 63, wave = tid >> 6;
    int l31 = lane & 31, lh = lane >> 5, l7 = lane & 7;

    if (tid < 64) es[tid] = 0.f;

    // ---- stage A tile 64x512 fp32 -> bf16, coalesced reads, swizzled writes ----
    const float4* A4 = (const float4*)A;
#pragma unroll
    for (int it = 0; it < 8; ++it) {
        int row = it * 8 + wave;                      // one row per wave-iteration
        size_t gidx = (size_t)(blockRow + row) * 128 + (size_t)lane * 2;
        float4 f0 = A4[gidx], f1 = A4[gidx + 1];
        uint4 u;
        u.x = pack2(f0.x, f0.y); u.y = pack2(f0.z, f0.w);
        u.z = pack2(f1.x, f1.y); u.w = pack2(f1.z, f1.w);
        ldsA[row * 64 + (lane ^ (row & 7))] = u;
    }
    __syncthreads();

    const short8* lds8 = (const short8*)ldsA;
    int base0 = l31 * 64;                             // rtile 0: rows 0..31
    int base1 = (32 + l31) * 64;                      // rtile 1: rows 32..63

    int n0 = wave * 64 + l31;                         // this lane's col (ctile 0)
    const short8* b0p = (const short8*)(Wb + (size_t)n0 * 512);
    const short8* b1p = (const short8*)(Wb + (size_t)(n0 + 32) * 512);
    f32x16 acc00 = {0.f}, acc01 = {0.f}, acc10 = {0.f}, acc11 = {0.f};
#pragma unroll
    for (int c = 0; c < 32; ++c) {                    // K chunks of 16
        int g = c * 2 + lh;                           // k-group of 8 for this lane
        int gx = g ^ l7;
        short8 a0 = lds8[base0 + gx];
        short8 a1 = lds8[base1 + gx];
        short8 b0 = b0p[g];
        short8 b1 = b1p[g];
        acc00 = __builtin_amdgcn_mfma_f32_32x32x16_bf16(a0, b0, acc00, 0, 0, 0);
        acc10 = __builtin_amdgcn_mfma_f32_32x32x16_bf16(a1, b0, acc10, 0, 0, 0);
        acc01 = __builtin_amdgcn_mfma_f32_32x32x16_bf16(a0, b1, acc01, 0, 0, 0);
        acc11 = __builtin_amdgcn_mfma_f32_32x32x16_bf16(a1, b1, acc11, 0, 0, 0);
    }

    // epilogue: tanh + Wscore dot, immediate width-32 reduce, atomicAdd to es.
    // C/D layout (32x32): col = lane&31, row = (r&3) + 8*(r>>2) + 4*lh
    float pp0 = pp[b * 512 + n0],      ws0 = wsc[n0];
    float pp1 = pp[b * 512 + n0 + 32], ws1 = wsc[n0 + 32];
#pragma unroll
    for (int r = 0; r < 16; ++r) {
        float v0 = tanh_fast(acc00[r] + pp0) * ws0 + tanh_fast(acc01[r] + pp1) * ws1;
        float v1 = tanh_fast(acc10[r] + pp0) * ws0 + tanh_fast(acc11[r] + pp1) * ws1;
#pragma unroll
        for (int off = 1; off < 32; off <<= 1) {
            v0 += __shfl_xor(v0, off, 32);
            v1 += __shfl_xor(v1, off, 32);
        }
        if (l31 == 0) {
            int row = lh * 4 + (r & 3) + 8 * (r >> 2);
            atomicAdd(&es[row],      v0);
            atomicAdd(&es[32 + row], v1);
        }
    }
    __syncthreads();
    if (tid < 64) e[blockRow + tid] = es[tid];
}

// ---------------- kernel 3: softmax over T (in-place on alpha buffer) --------
__global__ void k_softmax(float* __restrict__ ealpha) {
    __shared__ float red[8];
    int b = blockIdx.x, tid = threadIdx.x;           // 256 threads, 2 elems each
    float v0 = ealpha[b * 512 + tid];
    float v1 = ealpha[b * 512 + 256 + tid];
    float mx = fmaxf(v0, v1);
    for (int off = 32; off; off >>= 1) mx = fmaxf(mx, __shfl_xor(mx, off, 64));
    if ((tid & 63) == 0) red[tid >> 6] = mx;
    __syncthreads();
    mx = fmaxf(fmaxf(red[0], red[1]), fmaxf(red[2], red[3]));
    float x0 = __expf(v0 - mx), x1 = __expf(v1 - mx);
    float s = x0 + x1;
    for (int off = 32; off; off >>= 1) s += __shfl_xor(s, off, 64);
    if ((tid & 63) == 0) red[4 + (tid >> 6)] = s;
    __syncthreads();
    s = red[4] + red[5] + red[6] + red[7];
    float inv = 1.f / s;
    ealpha[b * 512 + tid]       = x0 * inv;
    ealpha[b * 512 + 256 + tid] = x1 * inv;
}

// ---------------- kernel 4: context = alpha^T batch_H ------------------------
__global__ void k_context(const float* __restrict__ A, const float* __restrict__ alpha,
                          float* __restrict__ ctx) {
    int b = blockIdx.x >> 3, chunk = blockIdx.x & 7;
    int tid = threadIdx.x;                            // 256 threads, 2 floats each
    const float2* A2 = (const float2*)A;
    float ax = 0.f, ay = 0.f;
    int t0 = chunk * 64;
    for (int t = 0; t < 64; ++t) {
        float a = alpha[b * 512 + t0 + t];            // uniform -> scalar load
        float2 v = A2[(size_t)(b * 512 + t0 + t) * 256 + tid];
        ax += a * v.x; ay += a * v.y;
    }
    atomicAdd(&ctx[b * 512 + tid * 2],     ax);
    atomicAdd(&ctx[b * 512 + tid * 2 + 1], ay);
}

// ---------------- kernel 5: gates = x@W_ih^T + h@W_hh^T + biases -------------
// virtual K=1120: x = [context(512) | onehot(96) | h(512)], B = [W_ih | W_hh]
__launch_bounds__(256)
__global__ void k_gates(const float* __restrict__ ctx, const float* __restrict__ oneh,
                        const float* __restrict__ hin,
                        const float* __restrict__ Wih, const float* __restrict__ Whh,
                        const float* __restrict__ bih, const float* __restrict__ bhh,
                        float* __restrict__ gates) {
    __shared__ float As[32][33];
    __shared__ float Bs[32][65];                      // padded: kills staging conflicts
    int bT = blockIdx.x;                              // 0..7  (batch tiles of 32)
    int gT = blockIdx.y;                              // 0..31 (gate tiles of 64)
    int tid = threadIdx.x;
    int col = tid & 63;                               // g within tile
    int rg = tid >> 6;                                // row group: rows rg*8..+7
    float acc[8] = {0, 0, 0, 0, 0, 0, 0, 0};
    for (int k0 = 0; k0 < 1120; k0 += 32) {
        for (int i = tid; i < 1024; i += 256) {       // A tile 32x32 (k-contiguous)
            int r = i >> 5, kk = i & 31;
            int bb = bT * 32 + r, k = k0 + kk;
            float v;
            if (k < 512)      v = ctx[bb * 512 + k];
            else if (k < 608) v = oneh[bb * 96 + (k - 512)];
            else              v = hin[bb * 512 + (k - 608)];
            As[r][kk] = v;
        }
        for (int i = tid; i < 2048; i += 256) {       // B tile: k-contiguous reads
            int gg = i >> 5, kk = i & 31;
            int g = gT * 64 + gg, k = k0 + kk;
            float v;
            if (k < 608) v = Wih[(size_t)g * 608 + k];
            else         v = Whh[(size_t)g * 512 + (k - 608)];
            Bs[kk][gg] = v;
        }
        __syncthreads();
#pragma unroll 8
        for (int kk = 0; kk < 32; ++kk) {
            float bv = Bs[kk][col];
#pragma unroll
            for (int r = 0; r < 8; ++r)
                acc[r] += As[rg * 8 + r][kk] * bv;
        }
        __syncthreads();
    }
    int g = gT * 64 + col;
    float bias = bih[g] + bhh[g];
#pragma unroll
    for (int r = 0; r < 8; ++r) {
        int bb = bT * 32 + rg * 8 + r;
        gates[(size_t)bb * 2048 + g] = acc[r] + bias;
    }
}

// ---------------- kernel 6: LSTM pointwise -----------------------------------
__global__ void k_lstm(const float* __restrict__ gates, const float* __restrict__ c,
                       float* __restrict__ out) {
    int i = blockIdx.x * 256 + threadIdx.x;           // 131072
    int b = i >> 9, u = i & 511;
    const float* g = gates + (size_t)b * 2048;
    float si = sigmoid_fast(g[u]);
    float sf = sigmoid_fast(g[512 + u]);
    float tg = tanh_fast(g[1024 + u]);
    float so = sigmoid_fast(g[1536 + u]);
    float cn = sf * c[i] + si * tg;
    float hn = so * tanh_fast(cn);
    out[i] = hn;                                      // h_new
    out[BT + i] = cn;                                 // c_new
}

extern "C" void kernel_launch(void* const* d_in, const int* in_sizes, int n_in,
                              void* d_out, int out_size, void* d_ws, size_t ws_size,
                              hipStream_t stream) {
    const float* hin  = (const float*)d_in[0];
    const float* c    = (const float*)d_in[1];
    const float* bH   = (const float*)d_in[2];
    const float* oneh = (const float*)d_in[3];
    const float* Wi2h = (const float*)d_in[4];
    const float* Wh2h = (const float*)d_in[5];
    const float* bh2h = (const float*)d_in[6];
    const float* Wsc  = (const float*)d_in[7];
    const float* Wih  = (const float*)d_in[8];
    const float* Whh  = (const float*)d_in[9];
    const float* bih  = (const float*)d_in[10];
    const float* bhh  = (const float*)d_in[11];
    float* out = (float*)d_out;
    float* alpha = out + 2 * BT;                      // output slot 3; also holds e

    char* w = (char*)d_ws;                            // needs 3.67 MB of ws
    unsigned* Wb  = (unsigned*)w;                     // bf16 Wi2h, 512 KB
    float* pp     = (float*)(w + 524288);             // [B_,512]
    float* ctx    = (float*)(w + 1048576);            // [B_,512]
    float* gates  = (float*)(w + 1572864);            // [B_,2048], 2 MB

    hipMemsetAsync(ctx, 0, 524288, stream);           // context accumulated via atomics
    k_cvt     <<<512, 256, 0, stream>>>(Wi2h, Wb);
    k_prevproj<<<4096, 256, 0, stream>>>(hin, Wh2h, bh2h, pp);
    k_scores  <<<2048, 512, 0, stream>>>(bH, (const unsigned short*)Wb, pp, Wsc, alpha);
    k_softmax <<<256, 256, 0, stream>>>(alpha);
    k_context <<<2048, 256, 0, stream>>>(bH, alpha, ctx);
    k_gates   <<<dim3(8, 32), 256, 0, stream>>>(ctx, oneh, hin, Wih, Whh, bih, bhh, gates);
    k_lstm    <<<512, 256, 0, stream>>>(gates, c, out);
}

// Round 4
// 571.615 us; speedup vs baseline: 1.4022x; 1.4022x over previous
//
#include <hip/hip_runtime.h>
#include <stdint.h>

// Problem constants
#define B_    256
#define T_    512
#define DIN   512
#define H_    512
#define NEMB_ 96
#define BT    131072   // B_*T_
#define KG    1120     // gates GEMM K = 512 + 96 + 512

typedef __attribute__((ext_vector_type(8))) short short8;    // 8 bf16 (4 VGPRs)
typedef __attribute__((ext_vector_type(4))) float f32x4;
typedef __attribute__((ext_vector_type(16))) float f32x16;

__device__ __forceinline__ unsigned bf16_rne(float f) {
    unsigned u = __float_as_uint(f);
    return (u + 0x7FFF + ((u >> 16) & 1)) >> 16;
}
__device__ __forceinline__ unsigned pack2(float a, float b) {
    return bf16_rne(a) | (bf16_rne(b) << 16);
}
__device__ __forceinline__ float tanh_fast(float x) {
    float ex = __expf(2.f * x);
    return 1.f - 2.f / (ex + 1.f);
}
__device__ __forceinline__ float sigmoid_fast(float x) {
    return 1.f / (1.f + __expf(-x));
}

// ---------------- kernel 0: Wi2h fp32 -> bf16 ----------------
__global__ void k_cvt(const float* __restrict__ W, unsigned* __restrict__ Wb) {
    int i = blockIdx.x * 256 + threadIdx.x;          // 131072 uints (2 bf16 each)
    float2 f = ((const float2*)W)[i];
    Wb[i] = pack2(f.x, f.y);
}

// ---------------- kernel 1: prevproj = h @ Wh2h^T + bh2h ----------------
__global__ void k_prevproj(const float* __restrict__ hin, const float* __restrict__ Whh,
                           const float* __restrict__ bh, float* __restrict__ pp) {
    __shared__ float hs[512];
    int b = blockIdx.x >> 4, tc = blockIdx.x & 15;
    int tid = threadIdx.x;
    hs[tid]       = hin[b * 512 + tid];
    hs[256 + tid] = hin[b * 512 + 256 + tid];
    __syncthreads();
    int wave = tid >> 6, lane = tid & 63;
    int o = lane >> 3, kg = lane & 7;
    int t = tc * 32 + wave * 8 + o;
    const float4* wr = (const float4*)(Whh + (size_t)t * 512);
    const float4* hv = (const float4*)hs;
    float acc = 0.f;
#pragma unroll
    for (int j = 0; j < 16; ++j) {
        float4 w = wr[j * 8 + kg];
        float4 x = hv[j * 8 + kg];
        acc += w.x * x.x + w.y * x.y + w.z * x.z + w.w * x.w;
    }
#pragma unroll
    for (int off = 1; off < 8; off <<= 1) acc += __shfl_xor(acc, off, 8);
    if (kg == 0) pp[b * 512 + t] = acc + bh[t];
}

// ---------------- kernel 2: attention scores (fused GEMM+tanh+dot) -----------
__launch_bounds__(512, 4)
__global__ void k_scores(const float* __restrict__ A,              // batch_H [BT,512]
                         const unsigned short* __restrict__ Wb,    // bf16 Wi2h [512,512]
                         const float* __restrict__ pp,             // [B_,512]
                         const float* __restrict__ wsc,            // Wscore [512]
                         float* __restrict__ e)                    // [BT]
{
    __shared__ uint4 ldsA[4096];                                   // 65536 B
    __shared__ float es[64];
    int tid = threadIdx.x;
    int blockRow = blockIdx.x * 64;
    int b = blockRow >> 9;                                         // 8 blocks per batch row
    int lane = tid & 63, wave = tid >> 6;
    int l31 = lane & 31, lh = lane >> 5, l7 = lane & 7;

    if (tid < 64) es[tid] = 0.f;

    const float4* A4 = (const float4*)A;
#pragma unroll
    for (int it = 0; it < 8; ++it) {
        int row = it * 8 + wave;
        size_t gidx = (size_t)(blockRow + row) * 128 + (size_t)lane * 2;
        float4 f0 = A4[gidx], f1 = A4[gidx + 1];
        uint4 u;
        u.x = pack2(f0.x, f0.y); u.y = pack2(f0.z, f0.w);
        u.z = pack2(f1.x, f1.y); u.w = pack2(f1.z, f1.w);
        ldsA[row * 64 + (lane ^ (row & 7))] = u;
    }
    __syncthreads();

    const short8* lds8 = (const short8*)ldsA;
    int base0 = l31 * 64;
    int base1 = (32 + l31) * 64;

    int n0 = wave * 64 + l31;
    const short8* b0p = (const short8*)(Wb + (size_t)n0 * 512);
    const short8* b1p = (const short8*)(Wb + (size_t)(n0 + 32) * 512);
    f32x16 acc00 = {0.f}, acc01 = {0.f}, acc10 = {0.f}, acc11 = {0.f};
#pragma unroll
    for (int c = 0; c < 32; ++c) {
        int g = c * 2 + lh;
        int gx = g ^ l7;
        short8 a0 = lds8[base0 + gx];
        short8 a1 = lds8[base1 + gx];
        short8 b0 = b0p[g];
        short8 b1 = b1p[g];
        acc00 = __builtin_amdgcn_mfma_f32_32x32x16_bf16(a0, b0, acc00, 0, 0, 0);
        acc10 = __builtin_amdgcn_mfma_f32_32x32x16_bf16(a1, b0, acc10, 0, 0, 0);
        acc01 = __builtin_amdgcn_mfma_f32_32x32x16_bf16(a0, b1, acc01, 0, 0, 0);
        acc11 = __builtin_amdgcn_mfma_f32_32x32x16_bf16(a1, b1, acc11, 0, 0, 0);
    }

    float pp0 = pp[b * 512 + n0],      ws0 = wsc[n0];
    float pp1 = pp[b * 512 + n0 + 32], ws1 = wsc[n0 + 32];
#pragma unroll
    for (int r = 0; r < 16; ++r) {
        float v0 = tanh_fast(acc00[r] + pp0) * ws0 + tanh_fast(acc01[r] + pp1) * ws1;
        float v1 = tanh_fast(acc10[r] + pp0) * ws0 + tanh_fast(acc11[r] + pp1) * ws1;
#pragma unroll
        for (int off = 1; off < 32; off <<= 1) {
            v0 += __shfl_xor(v0, off, 32);
            v1 += __shfl_xor(v1, off, 32);
        }
        if (l31 == 0) {
            int row = lh * 4 + (r & 3) + 8 * (r >> 2);
            atomicAdd(&es[row],      v0);
            atomicAdd(&es[32 + row], v1);
        }
    }
    __syncthreads();
    if (tid < 64) e[blockRow + tid] = es[tid];
}

// ---------------- kernel 3: softmax over T (in-place on alpha buffer) --------
__global__ void k_softmax(float* __restrict__ ealpha) {
    __shared__ float red[8];
    int b = blockIdx.x, tid = threadIdx.x;
    float v0 = ealpha[b * 512 + tid];
    float v1 = ealpha[b * 512 + 256 + tid];
    float mx = fmaxf(v0, v1);
    for (int off = 32; off; off >>= 1) mx = fmaxf(mx, __shfl_xor(mx, off, 64));
    if ((tid & 63) == 0) red[tid >> 6] = mx;
    __syncthreads();
    mx = fmaxf(fmaxf(red[0], red[1]), fmaxf(red[2], red[3]));
    float x0 = __expf(v0 - mx), x1 = __expf(v1 - mx);
    float s = x0 + x1;
    for (int off = 32; off; off >>= 1) s += __shfl_xor(s, off, 64);
    if ((tid & 63) == 0) red[4 + (tid >> 6)] = s;
    __syncthreads();
    s = red[4] + red[5] + red[6] + red[7];
    float inv = 1.f / s;
    ealpha[b * 512 + tid]       = x0 * inv;
    ealpha[b * 512 + 256 + tid] = x1 * inv;
}

// ---------------- kernel 4: context = alpha^T batch_H ------------------------
__global__ void k_context(const float* __restrict__ A, const float* __restrict__ alpha,
                          float* __restrict__ ctx) {
    int b = blockIdx.x >> 3, chunk = blockIdx.x & 7;
    int tid = threadIdx.x;
    const float2* A2 = (const float2*)A;
    float ax = 0.f, ay = 0.f;
    int t0 = chunk * 64;
    for (int t = 0; t < 64; ++t) {
        float a = alpha[b * 512 + t0 + t];
        float2 v = A2[(size_t)(b * 512 + t0 + t) * 256 + tid];
        ax += a * v.x; ay += a * v.y;
    }
    atomicAdd(&ctx[b * 512 + tid * 2],     ax);
    atomicAdd(&ctx[b * 512 + tid * 2 + 1], ay);
}

// ---------------- kernel 5a: xb = bf16([ctx | onehot | h])  [256,1120] -------
__global__ void k_xcat(const float* __restrict__ ctx, const float* __restrict__ oneh,
                       const float* __restrict__ hin, unsigned short* __restrict__ xb) {
    int b = blockIdx.x, tid = threadIdx.x;
    for (int k = tid; k < KG; k += 256) {
        float v;
        if (k < 512)      v = ctx[b * 512 + k];
        else if (k < 608) v = oneh[b * 96 + (k - 512)];
        else              v = hin[b * 512 + (k - 608)];
        xb[(size_t)b * KG + k] = (unsigned short)bf16_rne(v);
    }
}

// ---------------- kernel 5b: Wg = bf16([W_ih | W_hh])  [2048,1120] -----------
__global__ void k_wcat(const float* __restrict__ Wih, const float* __restrict__ Whh,
                       unsigned short* __restrict__ Wg) {
    int g = blockIdx.x, tid = threadIdx.x;
    for (int k = tid; k < KG; k += 256) {
        float v;
        if (k < 608) v = Wih[(size_t)g * 608 + k];
        else         v = Whh[(size_t)g * 512 + (k - 608)];
        Wg[(size_t)g * KG + k] = (unsigned short)bf16_rne(v);
    }
}

// ---------------- kernel 5c: gates partials via MFMA, split-K ----------------
// One wave per (32-batch x 32-gate x K-slice) tile; 5 K-slices of 224.
// wid = blockIdx.x*4+wave: gI = wid&63, bI = (wid>>6)&7, kI = wid>>9.
// No LDS, no barriers: A (xb) and B (Wg) fragments loaded straight from L2,
// 28 independent dwordx4 loads feeding 14 chained 32x32x16 MFMAs.
__launch_bounds__(256, 4)
__global__ void k_gates(const unsigned short* __restrict__ xb,
                        const unsigned short* __restrict__ Wg,
                        float* __restrict__ gates5) {       // [5][256][2048]
    int tid = threadIdx.x;
    int lane = tid & 63, wave = tid >> 6;
    int l31 = lane & 31, lh = lane >> 5;
    int wid = blockIdx.x * 4 + wave;
    int gI = wid & 63, bI = (wid >> 6) & 7, kI = wid >> 9;

    // row strides in short8 (16B) units: 1120/8 = 140; k-slice base kI*224/8 = kI*28
    const short8* ax = (const short8*)xb + (size_t)(bI * 32 + l31) * 140 + kI * 28;
    const short8* bx = (const short8*)Wg + (size_t)(gI * 32 + l31) * 140 + kI * 28;

    f32x16 acc = {0.f};
#pragma unroll
    for (int c = 0; c < 14; ++c) {
        short8 a = ax[c * 2 + lh];
        short8 b = bx[c * 2 + lh];
        acc = __builtin_amdgcn_mfma_f32_32x32x16_bf16(a, b, acc, 0, 0, 0);
    }
    // C layout: col(gate) = lane&31, row(batch) = (r&3) + 8*(r>>2) + 4*lh
    float* gout = gates5 + (size_t)kI * (B_ * 2048)
                + (size_t)(bI * 32 + 4 * lh) * 2048 + gI * 32 + l31;
#pragma unroll
    for (int r = 0; r < 16; ++r)
        gout[(size_t)((r & 3) + 8 * (r >> 2)) * 2048] = acc[r];
}

// ---------------- kernel 6: LSTM pointwise (sums 5 K-slices + biases) --------
__global__ void k_lstm(const float* __restrict__ gates5, const float* __restrict__ c,
                       const float* __restrict__ bih, const float* __restrict__ bhh,
                       float* __restrict__ out) {
    int i = blockIdx.x * 256 + threadIdx.x;           // 131072
    int b = i >> 9, u = i & 511;
    size_t base = (size_t)b * 2048 + u;
    float gi = bih[u]        + bhh[u];
    float gf = bih[512 + u]  + bhh[512 + u];
    float gg = bih[1024 + u] + bhh[1024 + u];
    float go = bih[1536 + u] + bhh[1536 + u];
#pragma unroll
    for (int s = 0; s < 5; ++s) {
        const float* g = gates5 + (size_t)s * (B_ * 2048) + base;
        gi += g[0]; gf += g[512]; gg += g[1024]; go += g[1536];
    }
    float si = sigmoid_fast(gi);
    float sf = sigmoid_fast(gf);
    float tg = tanh_fast(gg);
    float so = sigmoid_fast(go);
    float cn = sf * c[i] + si * tg;
    float hn = so * tanh_fast(cn);
    out[i] = hn;                                      // h_new
    out[BT + i] = cn;                                 // c_new
}

extern "C" void kernel_launch(void* const* d_in, const int* in_sizes, int n_in,
                              void* d_out, int out_size, void* d_ws, size_t ws_size,
                              hipStream_t stream) {
    const float* hin  = (const float*)d_in[0];
    const float* c    = (const float*)d_in[1];
    const float* bH   = (const float*)d_in[2];
    const float* oneh = (const float*)d_in[3];
    const float* Wi2h = (const float*)d_in[4];
    const float* Wh2h = (const float*)d_in[5];
    const float* bh2h = (const float*)d_in[6];
    const float* Wsc  = (const float*)d_in[7];
    const float* Wih  = (const float*)d_in[8];
    const float* Whh  = (const float*)d_in[9];
    const float* bih  = (const float*)d_in[10];
    const float* bhh  = (const float*)d_in[11];
    float* out = (float*)d_out;
    float* alpha = out + 2 * BT;                      // output slot 3; also holds e

    char* w = (char*)d_ws;                            // ~16.5 MB of ws used
    unsigned* Wb          = (unsigned*)w;             // bf16 Wi2h, 512 KB
    float* pp             = (float*)(w + 524288);     // [B_,512]
    float* ctx            = (float*)(w + 1048576);    // [B_,512]
    unsigned short* xb    = (unsigned short*)(w + 1572864);  // [256,1120] bf16, 560 KB
    unsigned short* Wg    = (unsigned short*)(w + 2146304);  // [2048,1120] bf16, 4.59 MB
    float* gates5         = (float*)(w + 6733824);    // [5][256][2048] fp32, 10 MB

    hipMemsetAsync(ctx, 0, 524288, stream);           // context accumulated via atomics
    k_cvt     <<<512, 256, 0, stream>>>(Wi2h, Wb);
    k_wcat    <<<2048, 256, 0, stream>>>(Wih, Whh, Wg);
    k_prevproj<<<4096, 256, 0, stream>>>(hin, Wh2h, bh2h, pp);
    k_scores  <<<2048, 512, 0, stream>>>(bH, (const unsigned short*)Wb, pp, Wsc, alpha);
    k_softmax <<<256, 256, 0, stream>>>(alpha);
    k_context <<<2048, 256, 0, stream>>>(bH, alpha, ctx);
    k_xcat    <<<256, 256, 0, stream>>>(ctx, oneh, hin, xb);
    k_gates   <<<640, 256, 0, stream>>>(xb, Wg, gates5);
    k_lstm    <<<512, 256, 0, stream>>>(gates5, c, bih, bhh, out);
}

// Round 5
// 526.967 us; speedup vs baseline: 1.5210x; 1.0847x over previous
//
#include <hip/hip_runtime.h>
#include <stdint.h>

// Problem constants
#define B_    256
#define T_    512
#define DIN   512
#define H_    512
#define NEMB_ 96
#define BT    131072   // B_*T_
#define KG    1120     // gates GEMM K = 512 + 96 + 512  (70 chunks of 16)

typedef __attribute__((ext_vector_type(8))) short short8;    // 8 bf16 (4 VGPRs)
typedef __attribute__((ext_vector_type(4))) float f32x4;
typedef __attribute__((ext_vector_type(16))) float f32x16;

__device__ __forceinline__ unsigned bf16_rne(float f) {
    unsigned u = __float_as_uint(f);
    return (u + 0x7FFF + ((u >> 16) & 1)) >> 16;
}
__device__ __forceinline__ unsigned pack2(float a, float b) {
    return bf16_rne(a) | (bf16_rne(b) << 16);
}
__device__ __forceinline__ uint4 pack8(float4 f0, float4 f1) {
    uint4 u;
    u.x = pack2(f0.x, f0.y); u.y = pack2(f0.z, f0.w);
    u.z = pack2(f1.x, f1.y); u.w = pack2(f1.z, f1.w);
    return u;
}
__device__ __forceinline__ float tanh_fast(float x) {
    float ex = __expf(2.f * x);
    return 1.f - 2.f / (ex + 1.f);
}
__device__ __forceinline__ float sigmoid_fast(float x) {
    return 1.f / (1.f + __expf(-x));
}

// ---- kernel 0: Wi2h fp32 -> bf16 in MFMA B-fragment order -------------------
// Wbf[nt][c][lane] (short8): value = Wi2h[nt*32 + (lane&31)][(c*2 + (lane>>5))*8 + j]
// nt = 32-col tile (16), c = K-chunk of 16 (32). One short8 per thread.
__global__ void k_bswz(const float* __restrict__ W, uint4* __restrict__ Wbf) {
    int u = blockIdx.x * 256 + threadIdx.x;          // 0..32767
    int l = u & 63, c = (u >> 6) & 31, nt = u >> 11;
    int row = nt * 32 + (l & 31);
    int k0 = (c * 2 + (l >> 5)) * 8;
    const float4* W4 = (const float4*)(W + (size_t)row * 512 + k0);
    Wbf[u] = pack8(W4[0], W4[1]);
}

// ---- kernel 1: prevproj = h @ Wh2h^T + bh2h ---------------------------------
__global__ void k_prevproj(const float* __restrict__ hin, const float* __restrict__ Whh,
                           const float* __restrict__ bh, float* __restrict__ pp) {
    __shared__ float hs[512];
    int b = blockIdx.x >> 4, tc = blockIdx.x & 15;
    int tid = threadIdx.x;
    hs[tid]       = hin[b * 512 + tid];
    hs[256 + tid] = hin[b * 512 + 256 + tid];
    __syncthreads();
    int wave = tid >> 6, lane = tid & 63;
    int o = lane >> 3, kg = lane & 7;
    int t = tc * 32 + wave * 8 + o;
    const float4* wr = (const float4*)(Whh + (size_t)t * 512);
    const float4* hv = (const float4*)hs;
    float acc = 0.f;
#pragma unroll
    for (int j = 0; j < 16; ++j) {
        float4 w = wr[j * 8 + kg];
        float4 x = hv[j * 8 + kg];
        acc += w.x * x.x + w.y * x.y + w.z * x.z + w.w * x.w;
    }
#pragma unroll
    for (int off = 1; off < 8; off <<= 1) acc += __shfl_xor(acc, off, 8);
    if (kg == 0) pp[b * 512 + t] = acc + bh[t];
}

// ---- kernel 2: attention scores (fused GEMM+tanh+dot) -----------------------
// e[b,t] = sum_h Wscore[h] * tanh( sum_d batch_H[b,t,d]*Wi2h[h,d] + pp[b,h] )
// BM=64 rows/block, 8 waves; wave w owns col tiles 2w,2w+1 (64 cols).
// B loads now stream from the fragment tensor: 1KB contiguous per instr.
__launch_bounds__(512, 4)
__global__ void k_scores(const float* __restrict__ A,              // batch_H [BT,512]
                         const uint4* __restrict__ Wbf,            // frag Wi2h
                         const float* __restrict__ pp,             // [B_,512]
                         const float* __restrict__ wsc,            // Wscore [512]
                         float* __restrict__ e)                    // [BT]
{
    __shared__ uint4 ldsA[4096];                                   // 65536 B
    __shared__ float es[64];
    int tid = threadIdx.x;
    int blockRow = blockIdx.x * 64;
    int b = blockRow >> 9;                                         // 8 blocks per batch row
    int lane = tid & 63, wave = tid >> 6;
    int l31 = lane & 31, lh = lane >> 5, l7 = lane & 7;

    if (tid < 64) es[tid] = 0.f;

    const float4* A4 = (const float4*)A;
#pragma unroll
    for (int it = 0; it < 8; ++it) {
        int row = it * 8 + wave;
        size_t gidx = (size_t)(blockRow + row) * 128 + (size_t)lane * 2;
        float4 f0 = A4[gidx], f1 = A4[gidx + 1];
        ldsA[row * 64 + (lane ^ (row & 7))] = pack8(f0, f1);
    }
    __syncthreads();

    const short8* lds8 = (const short8*)ldsA;
    int base0 = l31 * 64;
    int base1 = (32 + l31) * 64;

    const short8* wf = (const short8*)Wbf + wave * 4096 + lane;    // tiles 2w,2w+1
    f32x16 acc00 = {0.f}, acc01 = {0.f}, acc10 = {0.f}, acc11 = {0.f};
#pragma unroll
    for (int c = 0; c < 32; ++c) {
        int g = c * 2 + lh;
        int gx = g ^ l7;
        short8 a0 = lds8[base0 + gx];
        short8 a1 = lds8[base1 + gx];
        short8 b0 = wf[c * 64];                       // col tile 2w, chunk c
        short8 b1 = wf[2048 + c * 64];                // col tile 2w+1
        acc00 = __builtin_amdgcn_mfma_f32_32x32x16_bf16(a0, b0, acc00, 0, 0, 0);
        acc10 = __builtin_amdgcn_mfma_f32_32x32x16_bf16(a1, b0, acc10, 0, 0, 0);
        acc01 = __builtin_amdgcn_mfma_f32_32x32x16_bf16(a0, b1, acc01, 0, 0, 0);
        acc11 = __builtin_amdgcn_mfma_f32_32x32x16_bf16(a1, b1, acc11, 0, 0, 0);
    }

    int n0 = wave * 64 + l31;
    float pp0 = pp[b * 512 + n0],      ws0 = wsc[n0];
    float pp1 = pp[b * 512 + n0 + 32], ws1 = wsc[n0 + 32];
#pragma unroll
    for (int r = 0; r < 16; ++r) {
        float v0 = tanh_fast(acc00[r] + pp0) * ws0 + tanh_fast(acc01[r] + pp1) * ws1;
        float v1 = tanh_fast(acc10[r] + pp0) * ws0 + tanh_fast(acc11[r] + pp1) * ws1;
#pragma unroll
        for (int off = 1; off < 32; off <<= 1) {
            v0 += __shfl_xor(v0, off, 32);
            v1 += __shfl_xor(v1, off, 32);
        }
        if (l31 == 0) {
            int row = lh * 4 + (r & 3) + 8 * (r >> 2);
            atomicAdd(&es[row],      v0);
            atomicAdd(&es[32 + row], v1);
        }
    }
    __syncthreads();
    if (tid < 64) e[blockRow + tid] = es[tid];
}

// ---- kernel 3: softmax over T (in-place on alpha buffer) --------------------
__global__ void k_softmax(float* __restrict__ ealpha) {
    __shared__ float red[8];
    int b = blockIdx.x, tid = threadIdx.x;
    float v0 = ealpha[b * 512 + tid];
    float v1 = ealpha[b * 512 + 256 + tid];
    float mx = fmaxf(v0, v1);
    for (int off = 32; off; off >>= 1) mx = fmaxf(mx, __shfl_xor(mx, off, 64));
    if ((tid & 63) == 0) red[tid >> 6] = mx;
    __syncthreads();
    mx = fmaxf(fmaxf(red[0], red[1]), fmaxf(red[2], red[3]));
    float x0 = __expf(v0 - mx), x1 = __expf(v1 - mx);
    float s = x0 + x1;
    for (int off = 32; off; off >>= 1) s += __shfl_xor(s, off, 64);
    if ((tid & 63) == 0) red[4 + (tid >> 6)] = s;
    __syncthreads();
    s = red[4] + red[5] + red[6] + red[7];
    float inv = 1.f / s;
    ealpha[b * 512 + tid]       = x0 * inv;
    ealpha[b * 512 + 256 + tid] = x1 * inv;
}

// ---- kernel 4: context = alpha^T batch_H ------------------------------------
// 512 blocks = (b, 256-col half). 4 waves split T (stride 4); float4 loads
// (1KB/wave/instr), wave-uniform alpha scalar, LDS combine. No atomics.
__global__ void k_context(const float* __restrict__ A, const float* __restrict__ alpha,
                          float* __restrict__ ctx) {
    __shared__ float4 part[4][64];
    int b = blockIdx.x >> 1, half = blockIdx.x & 1;
    int tid = threadIdx.x, wave = tid >> 6, lane = tid & 63;
    const float4* A4 = (const float4*)A;
    const float* al = alpha + b * 512;
    size_t rbase = (size_t)b * 512;
    float4 acc = {0.f, 0.f, 0.f, 0.f};
#pragma unroll 8
    for (int t = wave; t < 512; t += 4) {
        float a = al[t];
        float4 v = A4[(rbase + t) * 128 + half * 64 + lane];
        acc.x += a * v.x; acc.y += a * v.y; acc.z += a * v.z; acc.w += a * v.w;
    }
    part[wave][lane] = acc;
    __syncthreads();
    if (tid < 64) {
        float4 p0 = part[0][tid], p1 = part[1][tid], p2 = part[2][tid], p3 = part[3][tid];
        float4 r;
        r.x = p0.x + p1.x + p2.x + p3.x;
        r.y = p0.y + p1.y + p2.y + p3.y;
        r.z = p0.z + p1.z + p2.z + p3.z;
        r.w = p0.w + p1.w + p2.w + p3.w;
        ((float4*)ctx)[b * 128 + half * 64 + tid] = r;
    }
}

// ---- kernel 5a: xbf = bf16 fragments of [ctx | onehot | h]  -----------------
// xbf[bt][c][lane] (short8): value = x[bt*32 + (lane&31)][(c*2+(lane>>5))*8+j]
// bt = 8 batch tiles, c = 70 K-chunks. Segment starts (0,512,608) are 8-aligned.
__global__ void k_xcat(const float* __restrict__ ctx, const float* __restrict__ oneh,
                       const float* __restrict__ hin, uint4* __restrict__ xbf) {
    int u = blockIdx.x * 256 + threadIdx.x;          // 0..35839
    int l = u & 63, r = u >> 6;
    int c = r % 70, bt = r / 70;
    int row = bt * 32 + (l & 31);
    int k0 = (c * 2 + (l >> 5)) * 8;
    const float4* s4;
    if (k0 < 512)      s4 = (const float4*)(ctx  + (size_t)row * 512 + k0);
    else if (k0 < 608) s4 = (const float4*)(oneh + (size_t)row * 96  + (k0 - 512));
    else               s4 = (const float4*)(hin  + (size_t)row * 512 + (k0 - 608));
    xbf[u] = pack8(s4[0], s4[1]);
}

// ---- kernel 5b: wgf = bf16 fragments of [W_ih | W_hh]  ----------------------
// wgf[gt][c][lane] (short8): gt = 64 gate tiles, c = 70 K-chunks.
__global__ void k_wcat(const float* __restrict__ Wih, const float* __restrict__ Whh,
                       uint4* __restrict__ wgf) {
    int u = blockIdx.x * 256 + threadIdx.x;          // 0..286719
    int l = u & 63, r = u >> 6;
    int c = r % 70, gt = r / 70;
    int g = gt * 32 + (l & 31);
    int k0 = (c * 2 + (l >> 5)) * 8;
    const float4* s4;
    if (k0 < 608) s4 = (const float4*)(Wih + (size_t)g * 608 + k0);
    else          s4 = (const float4*)(Whh + (size_t)g * 512 + (k0 - 608));
    wgf[u] = pack8(s4[0], s4[1]);
}

// ---- kernel 5c: gates partials via MFMA, split-K ----------------------------
// One wave per (32-batch x 32-gate x K-slice); 5 slices of 14 chunks.
// Both operands stream coalesced from fragment tensors. No LDS, no barriers.
__launch_bounds__(256, 4)
__global__ void k_gates(const uint4* __restrict__ xbf,
                        const uint4* __restrict__ wgf,
                        float* __restrict__ gates5) {       // [5][256][2048]
    int tid = threadIdx.x;
    int lane = tid & 63, wave = tid >> 6;
    int l31 = lane & 31, lh = lane >> 5;
    int wid = blockIdx.x * 4 + wave;
    int gI = wid & 63, bI = (wid >> 6) & 7, kI = wid >> 9;

    const short8* ax = (const short8*)xbf + (size_t)(bI * 70 + kI * 14) * 64 + lane;
    const short8* bx = (const short8*)wgf + (size_t)(gI * 70 + kI * 14) * 64 + lane;

    f32x16 acc = {0.f};
#pragma unroll
    for (int c = 0; c < 14; ++c) {
        short8 a = ax[c * 64];
        short8 b = bx[c * 64];
        acc = __builtin_amdgcn_mfma_f32_32x32x16_bf16(a, b, acc, 0, 0, 0);
    }
    // C layout: col(gate) = lane&31, row(batch) = (r&3) + 8*(r>>2) + 4*lh
    float* gout = gates5 + (size_t)kI * (B_ * 2048)
                + (size_t)(bI * 32 + 4 * lh) * 2048 + gI * 32 + l31;
#pragma unroll
    for (int r = 0; r < 16; ++r)
        gout[(size_t)((r & 3) + 8 * (r >> 2)) * 2048] = acc[r];
}

// ---- kernel 6: LSTM pointwise (sums 5 K-slices + biases) --------------------
__global__ void k_lstm(const float* __restrict__ gates5, const float* __restrict__ c,
                       const float* __restrict__ bih, const float* __restrict__ bhh,
                       float* __restrict__ out) {
    int i = blockIdx.x * 256 + threadIdx.x;           // 131072
    int b = i >> 9, u = i & 511;
    size_t base = (size_t)b * 2048 + u;
    float gi = bih[u]        + bhh[u];
    float gf = bih[512 + u]  + bhh[512 + u];
    float gg = bih[1024 + u] + bhh[1024 + u];
    float go = bih[1536 + u] + bhh[1536 + u];
#pragma unroll
    for (int s = 0; s < 5; ++s) {
        const float* g = gates5 + (size_t)s * (B_ * 2048) + base;
        gi += g[0]; gf += g[512]; gg += g[1024]; go += g[1536];
    }
    float si = sigmoid_fast(gi);
    float sf = sigmoid_fast(gf);
    float tg = tanh_fast(gg);
    float so = sigmoid_fast(go);
    float cn = sf * c[i] + si * tg;
    float hn = so * tanh_fast(cn);
    out[i] = hn;                                      // h_new
    out[BT + i] = cn;                                 // c_new
}

extern "C" void kernel_launch(void* const* d_in, const int* in_sizes, int n_in,
                              void* d_out, int out_size, void* d_ws, size_t ws_size,
                              hipStream_t stream) {
    const float* hin  = (const float*)d_in[0];
    const float* c    = (const float*)d_in[1];
    const float* bH   = (const float*)d_in[2];
    const float* oneh = (const float*)d_in[3];
    const float* Wi2h = (const float*)d_in[4];
    const float* Wh2h = (const float*)d_in[5];
    const float* bh2h = (const float*)d_in[6];
    const float* Wsc  = (const float*)d_in[7];
    const float* Wih  = (const float*)d_in[8];
    const float* Whh  = (const float*)d_in[9];
    const float* bih  = (const float*)d_in[10];
    const float* bhh  = (const float*)d_in[11];
    float* out = (float*)d_out;
    float* alpha = out + 2 * BT;                      // output slot 3; also holds e

    char* w = (char*)d_ws;                            // ~17.2 MB of ws used
    uint4* Wbf    = (uint4*)w;                        // frag Wi2h bf16, 512 KB
    float* pp     = (float*)(w + 524288);             // [B_,512]
    float* ctx    = (float*)(w + 1048576);            // [B_,512]
    uint4* xbf    = (uint4*)(w + 1572864);            // [8][70][64] short8, 560 KB
    uint4* wgf    = (uint4*)(w + 2146304);            // [64][70][64] short8, 4.59 MB
    float* gates5 = (float*)(w + 6733824);            // [5][256][2048] fp32, 10 MB

    k_bswz    <<<128, 256, 0, stream>>>(Wi2h, Wbf);
    k_wcat    <<<1120, 256, 0, stream>>>(Wih, Whh, wgf);
    k_prevproj<<<4096, 256, 0, stream>>>(hin, Wh2h, bh2h, pp);
    k_scores  <<<2048, 512, 0, stream>>>(bH, Wbf, pp, Wsc, alpha);
    k_softmax <<<256, 256, 0, stream>>>(alpha);
    k_context <<<512, 256, 0, stream>>>(bH, alpha, ctx);
    k_xcat    <<<140, 256, 0, stream>>>(ctx, oneh, hin, xbf);
    k_gates   <<<640, 256, 0, stream>>>(xbf, wgf, gates5);
    k_lstm    <<<512, 256, 0, stream>>>(gates5, c, bih, bhh, out);
}